// Round 1
// baseline (275.215 us; speedup 1.0000x reference)
//
#include <hip/hip_runtime.h>

typedef unsigned int u32;
typedef unsigned short u16;
typedef short s16x8 __attribute__((ext_vector_type(8)));
typedef float f32x4 __attribute__((ext_vector_type(4)));

#define BETA_MIN 0.1f
#define BETA_MAX 20.0f

#define MFMA16(a, b, c) __builtin_amdgcn_mfma_f32_16x16x32_bf16(a, b, c, 0, 0, 0)

__device__ __forceinline__ u16 f2bf(float f) {
    u32 u = __float_as_uint(f);
    u32 r = u + 0x7FFFu + ((u >> 16) & 1u);   // round-to-nearest-even on bf16 boundary
    return (u16)(r >> 16);
}
__device__ __forceinline__ float bf2f(u16 h) {
    return __uint_as_float(((u32)h) << 16);
}
__device__ __forceinline__ f32x4 zero4() {
    f32x4 z = {0.f, 0.f, 0.f, 0.f};
    return z;
}

// ---------------------------------------------------------------- prep kernels

// Per-row VP-SDE constants: rowc[n] = {a = mean*inv_var, b = -0.5*mean^2*inv_var, inv_var, 0}
__global__ void rows_kernel(const float* __restrict__ t, float* __restrict__ rowc, int N) {
    int n = blockIdx.x * blockDim.x + threadIdx.x;
    if (n >= N) return;
    float tv   = t[n];
    float lm   = -0.25f * tv * tv * (BETA_MAX - BETA_MIN) - 0.5f * tv * BETA_MIN;
    float mean = __expf(lm);
    float e2   = __expf(2.0f * lm);
    float s2   = fmaxf(1.0f - e2, 1e-12f);
    float iv   = 1.0f / s2;
    rowc[n * 4 + 0] = mean * iv;
    rowc[n * 4 + 1] = -0.5f * mean * mean * iv;
    rowc[n * 4 + 2] = iv;
    rowc[n * 4 + 3] = 0.f;
}

// fp32 -> (hi bf16, lo bf16 of residual), vectorized float4
__global__ void conv_hilo(const float* __restrict__ src, u16* __restrict__ hi,
                          u16* __restrict__ lo, int total4) {
    int idx = blockIdx.x * blockDim.x + threadIdx.x;
    if (idx >= total4) return;
    float4 v = ((const float4*)src)[idx];
    float f[4] = {v.x, v.y, v.z, v.w};
    u32 hp[2], lp[2];
    u16 h[4], l[4];
#pragma unroll
    for (int j = 0; j < 4; ++j) {
        h[j] = f2bf(f[j]);
        l[j] = f2bf(f[j] - bf2f(h[j]));
    }
    hp[0] = (u32)h[0] | ((u32)h[1] << 16);
    hp[1] = (u32)h[2] | ((u32)h[3] << 16);
    lp[0] = (u32)l[0] | ((u32)l[1] << 16);
    lp[1] = (u32)l[2] | ((u32)l[3] << 16);
    ((uint2*)hi)[idx] = make_uint2(hp[0], hp[1]);
    ((uint2*)lo)[idx] = make_uint2(lp[0], lp[1]);
}

// Vt[d][m] = bf16(train[m][d]) (D x M, for PV B-fragment reads); y2[m] = ||y_m||^2
// one wave per row m; block = 4 waves
__global__ void vt_y2_kernel(const float* __restrict__ train, u16* __restrict__ Vt,
                             float* __restrict__ y2, int M) {
    int wave = threadIdx.x >> 6, lane = threadIdx.x & 63;
    int m = blockIdx.x * 4 + wave;
    const float* row = train + (size_t)m * 128;
    float2 v = *(const float2*)(row + lane * 2);
    u16 h0 = f2bf(v.x), h1 = f2bf(v.y);
    Vt[(size_t)(lane * 2 + 0) * M + m] = h0;
    Vt[(size_t)(lane * 2 + 1) * M + m] = h1;
    float s = v.x * v.x + v.y * v.y;
#pragma unroll
    for (int d = 1; d < 64; d <<= 1) s += __shfl_xor(s, d);
    if (lane == 0) y2[m] = s;
}

// ---------------------------------------------------------------- flash kernel
// grid = (N/128, split); block = 256 (4 waves, 32 q-rows/wave); K-tile = 32 points.
// S = a_n * (Qhi*Khi + Qlo*Khi + Qhi*Klo) + b_n * y2[m]  (bf16x3 split precision)
__global__ __launch_bounds__(256)
void flash_kernel(const u16* __restrict__ Khi, const u16* __restrict__ Klo,
                  const u16* __restrict__ Vt,  const u16* __restrict__ Qhi,
                  const u16* __restrict__ Qlo, const float* __restrict__ rowc,
                  const float* __restrict__ y2, float* __restrict__ partO,
                  float* __restrict__ partML, int N, int M, int mchunk) {
    __shared__ u16 sKhi[32][136];      // +8 pad: 16B-aligned rows, breaks stride-128 banks
    __shared__ u16 sKlo[32][136];
    __shared__ u16 sVt[128][40];       // V transposed: [d][m], pad 32->40
    __shared__ u16 sP[4][2][16][40];   // per-wave, per-qsub P tile (C-layout -> A-layout)

    const int tid  = threadIdx.x;
    const int wave = tid >> 6, lane = tid & 63;
    const int l15  = lane & 15, quad = lane >> 4;
    const int qb = blockIdx.x, chunk = blockIdx.y;
    const int q0 = qb * 128 + wave * 32;
    const int m_begin = chunk * mchunk;

    // Q fragments in registers: A-layout A[m=l15][k=quad*8+j]
    s16x8 qh[2][4], ql[2][4];
#pragma unroll
    for (int i = 0; i < 2; ++i) {
        int row = q0 + i * 16 + l15;
        const u16* ph = Qhi + (size_t)row * 128;
        const u16* pl = Qlo + (size_t)row * 128;
#pragma unroll
        for (int kb = 0; kb < 4; ++kb) {
            qh[i][kb] = *(const s16x8*)(ph + kb * 32 + quad * 8);
            ql[i][kb] = *(const s16x8*)(pl + kb * 32 + quad * 8);
        }
    }
    float av[2][4], bv[2][4];
#pragma unroll
    for (int i = 0; i < 2; ++i)
#pragma unroll
        for (int k = 0; k < 4; ++k) {
            int r = q0 + i * 16 + quad * 4 + k;
            av[i][k] = rowc[r * 4 + 0];
            bv[i][k] = rowc[r * 4 + 1];
        }

    f32x4 O[2][8];
#pragma unroll
    for (int i = 0; i < 2; ++i)
#pragma unroll
        for (int db = 0; db < 8; ++db) O[i][db] = zero4();
    float m_run[2][4], l_run[2][4];
#pragma unroll
    for (int i = 0; i < 2; ++i)
#pragma unroll
        for (int k = 0; k < 4; ++k) { m_run[i][k] = -INFINITY; l_run[i][k] = 0.f; }

    for (int mt = 0; mt < mchunk; mt += 32) {
        const int m0 = m_begin + mt;
        __syncthreads();
        // stage K-tile (hi/lo) + Vt-tile; 512 16B-chunks each, 2 per thread
#pragma unroll
        for (int r = 0; r < 2; ++r) {
            int c = tid + r * 256;
            int row = c >> 4, col = (c & 15) * 8;
            *(uint4*)&sKhi[row][col] = *(const uint4*)(Khi + (size_t)(m0 + row) * 128 + col);
            *(uint4*)&sKlo[row][col] = *(const uint4*)(Klo + (size_t)(m0 + row) * 128 + col);
            int dd = c >> 2, mc = (c & 3) * 8;
            *(uint4*)&sVt[dd][mc] = *(const uint4*)(Vt + (size_t)dd * M + m0 + mc);
        }
        __syncthreads();

        float y2v0 = y2[m0 + l15];
        float y2v1 = y2[m0 + 16 + l15];

        // S GEMM: bf16x3
        f32x4 S[2][2];
#pragma unroll
        for (int i = 0; i < 2; ++i) { S[i][0] = zero4(); S[i][1] = zero4(); }
#pragma unroll
        for (int kb = 0; kb < 4; ++kb) {
            s16x8 bh0 = *(const s16x8*)&sKhi[l15][kb * 32 + quad * 8];
            s16x8 bh1 = *(const s16x8*)&sKhi[16 + l15][kb * 32 + quad * 8];
            s16x8 bl0 = *(const s16x8*)&sKlo[l15][kb * 32 + quad * 8];
            s16x8 bl1 = *(const s16x8*)&sKlo[16 + l15][kb * 32 + quad * 8];
#pragma unroll
            for (int i = 0; i < 2; ++i) {
                S[i][0] = MFMA16(qh[i][kb], bh0, S[i][0]);
                S[i][0] = MFMA16(ql[i][kb], bh0, S[i][0]);
                S[i][0] = MFMA16(qh[i][kb], bl0, S[i][0]);
                S[i][1] = MFMA16(qh[i][kb], bh1, S[i][1]);
                S[i][1] = MFMA16(ql[i][kb], bh1, S[i][1]);
                S[i][1] = MFMA16(qh[i][kb], bl1, S[i][1]);
            }
        }

        // online softmax; C-layout: row q = quad*4+k, col m = j*16+l15
#pragma unroll
        for (int i = 0; i < 2; ++i) {
#pragma unroll
            for (int k = 0; k < 4; ++k) {
                float s0 = av[i][k] * S[i][0][k] + bv[i][k] * y2v0;
                float s1 = av[i][k] * S[i][1][k] + bv[i][k] * y2v1;
                float rm = fmaxf(s0, s1);
                rm = fmaxf(rm, __shfl_xor(rm, 1));
                rm = fmaxf(rm, __shfl_xor(rm, 2));
                rm = fmaxf(rm, __shfl_xor(rm, 4));
                rm = fmaxf(rm, __shfl_xor(rm, 8));
                float mnew  = fmaxf(m_run[i][k], rm);
                float alpha = __expf(m_run[i][k] - mnew);   // exp(-inf)=0 on first tile
                float p0 = __expf(s0 - mnew);
                float p1 = __expf(s1 - mnew);
                float rs = p0 + p1;
                rs += __shfl_xor(rs, 1);
                rs += __shfl_xor(rs, 2);
                rs += __shfl_xor(rs, 4);
                rs += __shfl_xor(rs, 8);
                m_run[i][k] = mnew;
                l_run[i][k] = l_run[i][k] * alpha + rs;
                sP[wave][i][quad * 4 + k][l15]      = f2bf(p0);
                sP[wave][i][quad * 4 + k][16 + l15] = f2bf(p1);
#pragma unroll
                for (int db = 0; db < 8; ++db) O[i][db][k] *= alpha;
            }
        }
        // same-wave LDS write->read ordering (per-wave sP region, no barrier needed)
        asm volatile("s_waitcnt lgkmcnt(0)" ::: "memory");

        // PV: A = P (A-layout), B = Vt (B[k=m][n=d])
        s16x8 pa0 = *(const s16x8*)&sP[wave][0][l15][quad * 8];
        s16x8 pa1 = *(const s16x8*)&sP[wave][1][l15][quad * 8];
#pragma unroll
        for (int db = 0; db < 8; ++db) {
            s16x8 vb = *(const s16x8*)&sVt[db * 16 + l15][quad * 8];
            O[0][db] = MFMA16(pa0, vb, O[0][db]);
            O[1][db] = MFMA16(pa1, vb, O[1][db]);
        }
    }

    // epilogue: unnormalized O + (m, l) partials
#pragma unroll
    for (int i = 0; i < 2; ++i) {
#pragma unroll
        for (int db = 0; db < 8; ++db) {
#pragma unroll
            for (int k = 0; k < 4; ++k) {
                int row = q0 + i * 16 + quad * 4 + k;
                partO[((size_t)chunk * N + row) * 128 + db * 16 + l15] = O[i][db][k];
            }
        }
        if (l15 == 0) {
#pragma unroll
            for (int k = 0; k < 4; ++k) {
                int row = q0 + i * 16 + quad * 4 + k;
                partML[((size_t)chunk * N + row) * 2 + 0] = m_run[i][k];
                partML[((size_t)chunk * N + row) * 2 + 1] = l_run[i][k];
            }
        }
    }
}

// ---------------------------------------------------------------- combine
__global__ void combine_kernel(const float* __restrict__ partO, const float* __restrict__ partML,
                               const float* __restrict__ x, const float* __restrict__ rowc,
                               float* __restrict__ out, int N, int split) {
    int n = blockIdx.x, d = threadIdx.x;
    float Mx = -INFINITY;
    for (int c = 0; c < split; ++c)
        Mx = fmaxf(Mx, partML[((size_t)c * N + n) * 2]);
    float L = 0.f, acc = 0.f;
    for (int c = 0; c < split; ++c) {
        float w = __expf(partML[((size_t)c * N + n) * 2] - Mx);
        L   += w * partML[((size_t)c * N + n) * 2 + 1];
        acc += w * partO[((size_t)c * N + n) * 128 + d];
    }
    float evals = acc / L;
    if (evals != evals) evals = 0.f;   // match reference's isnan guard
    float iv = rowc[n * 4 + 2];
    out[(size_t)n * 128 + d] = (evals - x[(size_t)n * 128 + d]) * iv;
}

// ---------------------------------------------------------------- launch
extern "C" void kernel_launch(void* const* d_in, const int* in_sizes, int n_in,
                              void* d_out, int out_size, void* d_ws, size_t ws_size,
                              hipStream_t stream) {
    const float* x     = (const float*)d_in[0];
    const float* t     = (const float*)d_in[1];
    const float* train = (const float*)d_in[2];
    float* out = (float*)d_out;

    const int N = in_sizes[1];            // 4096
    const int D = 128;
    const int M = in_sizes[2] / D;        // 16384

    char* ws = (char*)d_ws;
    size_t off = 0;
    auto alloc = [&](size_t bytes) -> void* {
        void* p = ws + off;
        off = (off + bytes + 255) & ~(size_t)255;
        return p;
    };
    u16* Khi   = (u16*)alloc((size_t)M * D * 2);
    u16* Klo   = (u16*)alloc((size_t)M * D * 2);
    u16* Vt    = (u16*)alloc((size_t)M * D * 2);
    u16* Qhi   = (u16*)alloc((size_t)N * D * 2);
    u16* Qlo   = (u16*)alloc((size_t)N * D * 2);
    float* rowc = (float*)alloc((size_t)N * 16);
    float* y2   = (float*)alloc((size_t)M * 4);
    size_t base = off;
    size_t per  = (size_t)N * D * 4 + (size_t)N * 8 + 512;   // partO + partML per chunk
    int split = 16;
    while (split > 1 && base + per * split > ws_size) split >>= 1;
    float* partO  = (float*)alloc((size_t)split * N * D * 4);
    float* partML = (float*)alloc((size_t)split * N * 8);

    rows_kernel<<<(N + 255) / 256, 256, 0, stream>>>(t, rowc, N);
    conv_hilo<<<(N * D / 4 + 255) / 256, 256, 0, stream>>>(x, Qhi, Qlo, N * D / 4);
    conv_hilo<<<(M * D / 4 + 255) / 256, 256, 0, stream>>>(train, Khi, Klo, M * D / 4);
    vt_y2_kernel<<<M / 4, 256, 0, stream>>>(train, Vt, y2, M);

    int mchunk = M / split;
    dim3 grid(N / 128, split);
    flash_kernel<<<grid, 256, 0, stream>>>(Khi, Klo, Vt, Qhi, Qlo, rowc, y2,
                                           partO, partML, N, M, mchunk);
    combine_kernel<<<N, 128, 0, stream>>>(partO, partML, x, rowc, out, N, split);
}

// Round 2
// 211.168 us; speedup vs baseline: 1.3033x; 1.3033x over previous
//
#include <hip/hip_runtime.h>

typedef unsigned int u32;
typedef unsigned short u16;
typedef short s16x8 __attribute__((ext_vector_type(8)));
typedef float f32x4 __attribute__((ext_vector_type(4)));

#define BETA_MIN 0.1f
#define BETA_MAX 20.0f

#define MFMA16(a, b, c) __builtin_amdgcn_mfma_f32_16x16x32_bf16(a, b, c, 0, 0, 0)

__device__ __forceinline__ u16 f2bf(float f) {
    u32 u = __float_as_uint(f);
    u32 r = u + 0x7FFFu + ((u >> 16) & 1u);   // round-to-nearest-even on bf16 boundary
    return (u16)(r >> 16);
}
__device__ __forceinline__ float bf2f(u16 h) {
    return __uint_as_float(((u32)h) << 16);
}
__device__ __forceinline__ f32x4 zero4() {
    f32x4 z = {0.f, 0.f, 0.f, 0.f};
    return z;
}

// DPP lane-rotate within 16-lane rows; VALU-latency cross-lane (vs ds_swizzle ~100cyc)
template <int CTRL>
__device__ __forceinline__ float dppf(float x) {
    return __int_as_float(__builtin_amdgcn_update_dpp(
        0, __float_as_int(x), CTRL, 0xF, 0xF, false));
}
// reduce across the 16 contiguous lanes of a DPP row; all lanes get the result
__device__ __forceinline__ float rowmax16(float x) {
    x = fmaxf(x, dppf<0xB1>(x));    // quad_perm [1,0,3,2]  (xor 1)
    x = fmaxf(x, dppf<0x4E>(x));    // quad_perm [2,3,0,1]  (xor 2)
    x = fmaxf(x, dppf<0x124>(x));   // row_ror:4
    x = fmaxf(x, dppf<0x128>(x));   // row_ror:8
    return x;
}
__device__ __forceinline__ float rowsum16(float x) {
    x += dppf<0xB1>(x);
    x += dppf<0x4E>(x);
    x += dppf<0x124>(x);
    x += dppf<0x128>(x);
    return x;
}

// ---------------------------------------------------------------- prep kernels

// Per-row VP-SDE constants: rowc[n] = {a = mean*inv_var, b = -0.5*mean^2*inv_var, inv_var, 0}
__global__ void rows_kernel(const float* __restrict__ t, float* __restrict__ rowc, int N) {
    int n = blockIdx.x * blockDim.x + threadIdx.x;
    if (n >= N) return;
    float tv   = t[n];
    float lm   = -0.25f * tv * tv * (BETA_MAX - BETA_MIN) - 0.5f * tv * BETA_MIN;
    float mean = __expf(lm);
    float e2   = __expf(2.0f * lm);
    float s2   = fmaxf(1.0f - e2, 1e-12f);
    float iv   = 1.0f / s2;
    rowc[n * 4 + 0] = mean * iv;
    rowc[n * 4 + 1] = -0.5f * mean * mean * iv;
    rowc[n * 4 + 2] = iv;
    rowc[n * 4 + 3] = 0.f;
}

// fp32 -> (hi bf16, lo bf16 of residual), vectorized float4
__global__ void conv_hilo(const float* __restrict__ src, u16* __restrict__ hi,
                          u16* __restrict__ lo, int total4) {
    int idx = blockIdx.x * blockDim.x + threadIdx.x;
    if (idx >= total4) return;
    float4 v = ((const float4*)src)[idx];
    float f[4] = {v.x, v.y, v.z, v.w};
    u32 hp[2], lp[2];
    u16 h[4], l[4];
#pragma unroll
    for (int j = 0; j < 4; ++j) {
        h[j] = f2bf(f[j]);
        l[j] = f2bf(f[j] - bf2f(h[j]));
    }
    hp[0] = (u32)h[0] | ((u32)h[1] << 16);
    hp[1] = (u32)h[2] | ((u32)h[3] << 16);
    lp[0] = (u32)l[0] | ((u32)l[1] << 16);
    lp[1] = (u32)l[2] | ((u32)l[3] << 16);
    ((uint2*)hi)[idx] = make_uint2(hp[0], hp[1]);
    ((uint2*)lo)[idx] = make_uint2(lp[0], lp[1]);
}

// Vt[d][m] = bf16(train[m][d]) (D x M, for PV B-fragment reads); y2[m] = ||y_m||^2
// one wave per row m; block = 4 waves
__global__ void vt_y2_kernel(const float* __restrict__ train, u16* __restrict__ Vt,
                             float* __restrict__ y2, int M) {
    int wave = threadIdx.x >> 6, lane = threadIdx.x & 63;
    int m = blockIdx.x * 4 + wave;
    const float* row = train + (size_t)m * 128;
    float2 v = *(const float2*)(row + lane * 2);
    u16 h0 = f2bf(v.x), h1 = f2bf(v.y);
    Vt[(size_t)(lane * 2 + 0) * M + m] = h0;
    Vt[(size_t)(lane * 2 + 1) * M + m] = h1;
    float s = v.x * v.x + v.y * v.y;
#pragma unroll
    for (int d = 1; d < 64; d <<= 1) s += __shfl_xor(s, d);
    if (lane == 0) y2[m] = s;
}

// ---------------------------------------------------------------- flash kernel
// grid = (N/64, split); block = 256 (4 waves, 16 q-rows/wave); K-tile = 32 points.
// S = a_n * (Qhi*Khi + Qlo*Khi + Qhi*Klo) + b_n * y2[m]  (bf16x3 split precision)
// LDS = exactly 32 KB -> 4 blocks/CU; __launch_bounds__(256,4) caps VGPR at 128
// -> 16 waves/CU (was 8): latency hiding is the point of this shape.
__global__ __launch_bounds__(256, 4)
void flash_kernel(const u16* __restrict__ Khi, const u16* __restrict__ Klo,
                  const u16* __restrict__ Vt,  const u16* __restrict__ Qhi,
                  const u16* __restrict__ Qlo, const float* __restrict__ rowc,
                  const float* __restrict__ y2, float* __restrict__ partO,
                  float* __restrict__ partML, int N, int M, int mchunk) {
    __shared__ u16 sKhi[32][136];      // +8 pad: 16B-aligned rows
    __shared__ u16 sKlo[32][136];
    __shared__ u16 sVt[128][40];       // V transposed: [d][m], pad 32->40
    __shared__ u16 sP[4][16][40];      // per-wave P tile (C-layout -> A-layout)

    const int tid  = threadIdx.x;
    const int wave = tid >> 6, lane = tid & 63;
    const int l15  = lane & 15, quad = lane >> 4;
    const int qb = blockIdx.x, chunk = blockIdx.y;
    const int q0 = qb * 64 + wave * 16;
    const int m_begin = chunk * mchunk;

    // Q fragments in registers: A-layout A[m=l15][k=quad*8+j]
    s16x8 qh[4], ql[4];
    {
        int row = q0 + l15;
        const u16* ph = Qhi + (size_t)row * 128;
        const u16* pl = Qlo + (size_t)row * 128;
#pragma unroll
        for (int kb = 0; kb < 4; ++kb) {
            qh[kb] = *(const s16x8*)(ph + kb * 32 + quad * 8);
            ql[kb] = *(const s16x8*)(pl + kb * 32 + quad * 8);
        }
    }
    float av[4], bv[4];
#pragma unroll
    for (int k = 0; k < 4; ++k) {
        int r = q0 + quad * 4 + k;
        av[k] = rowc[r * 4 + 0];
        bv[k] = rowc[r * 4 + 1];
    }

    f32x4 O[8];
#pragma unroll
    for (int db = 0; db < 8; ++db) O[db] = zero4();
    float m_run[4], l_run[4];
#pragma unroll
    for (int k = 0; k < 4; ++k) { m_run[k] = -INFINITY; l_run[k] = 0.f; }

    for (int mt = 0; mt < mchunk; mt += 32) {
        const int m0 = m_begin + mt;
        __syncthreads();
        // stage K-tile (hi/lo) + Vt-tile; 512 16B-chunks each, 2 per thread
#pragma unroll
        for (int r = 0; r < 2; ++r) {
            int c = tid + r * 256;
            int row = c >> 4, col = (c & 15) * 8;
            *(uint4*)&sKhi[row][col] = *(const uint4*)(Khi + (size_t)(m0 + row) * 128 + col);
            *(uint4*)&sKlo[row][col] = *(const uint4*)(Klo + (size_t)(m0 + row) * 128 + col);
            int dd = c >> 2, mc = (c & 3) * 8;
            *(uint4*)&sVt[dd][mc] = *(const uint4*)(Vt + (size_t)dd * M + m0 + mc);
        }
        __syncthreads();

        float y2v0 = y2[m0 + l15];
        float y2v1 = y2[m0 + 16 + l15];

        // S GEMM: bf16x3
        f32x4 S[2];
        S[0] = zero4(); S[1] = zero4();
#pragma unroll
        for (int kb = 0; kb < 4; ++kb) {
            s16x8 bh0 = *(const s16x8*)&sKhi[l15][kb * 32 + quad * 8];
            s16x8 bh1 = *(const s16x8*)&sKhi[16 + l15][kb * 32 + quad * 8];
            s16x8 bl0 = *(const s16x8*)&sKlo[l15][kb * 32 + quad * 8];
            s16x8 bl1 = *(const s16x8*)&sKlo[16 + l15][kb * 32 + quad * 8];
            S[0] = MFMA16(qh[kb], bh0, S[0]);
            S[0] = MFMA16(ql[kb], bh0, S[0]);
            S[0] = MFMA16(qh[kb], bl0, S[0]);
            S[1] = MFMA16(qh[kb], bh1, S[1]);
            S[1] = MFMA16(ql[kb], bh1, S[1]);
            S[1] = MFMA16(qh[kb], bl1, S[1]);
        }

        // online softmax; C-layout: row q = quad*4+k (16 contiguous lanes = one DPP row)
#pragma unroll
        for (int k = 0; k < 4; ++k) {
            float s0 = av[k] * S[0][k] + bv[k] * y2v0;
            float s1 = av[k] * S[1][k] + bv[k] * y2v1;
            float rm    = rowmax16(fmaxf(s0, s1));
            float mnew  = fmaxf(m_run[k], rm);
            float alpha = __expf(m_run[k] - mnew);   // exp(-inf)=0 on first tile
            float p0 = __expf(s0 - mnew);
            float p1 = __expf(s1 - mnew);
            m_run[k] = mnew;
            // deferred row-sum: per-lane partial; alpha is row-uniform so this is exact
            l_run[k] = l_run[k] * alpha + (p0 + p1);
            sP[wave][quad * 4 + k][l15]      = f2bf(p0);
            sP[wave][quad * 4 + k][16 + l15] = f2bf(p1);
#pragma unroll
            for (int db = 0; db < 8; ++db) O[db][k] *= alpha;
        }
        // same-wave LDS write->read ordering (per-wave sP region, no barrier needed)
        asm volatile("s_waitcnt lgkmcnt(0)" ::: "memory");

        // PV: A = P (A-layout), B = Vt (B[k=m][n=d])
        s16x8 pa = *(const s16x8*)&sP[wave][l15][quad * 8];
#pragma unroll
        for (int db = 0; db < 8; ++db) {
            s16x8 vb = *(const s16x8*)&sVt[db * 16 + l15][quad * 8];
            O[db] = MFMA16(pa, vb, O[db]);
        }
    }

    // epilogue: unnormalized O + (m, l) partials
#pragma unroll
    for (int db = 0; db < 8; ++db) {
#pragma unroll
        for (int k = 0; k < 4; ++k) {
            int row = q0 + quad * 4 + k;
            partO[((size_t)chunk * N + row) * 128 + db * 16 + l15] = O[db][k];
        }
    }
#pragma unroll
    for (int k = 0; k < 4; ++k) {
        float lsum = rowsum16(l_run[k]);
        if (l15 == 0) {
            int row = q0 + quad * 4 + k;
            partML[((size_t)chunk * N + row) * 2 + 0] = m_run[k];
            partML[((size_t)chunk * N + row) * 2 + 1] = lsum;
        }
    }
}

// ---------------------------------------------------------------- combine
__global__ void combine_kernel(const float* __restrict__ partO, const float* __restrict__ partML,
                               const float* __restrict__ x, const float* __restrict__ rowc,
                               float* __restrict__ out, int N, int split) {
    int n = blockIdx.x, d = threadIdx.x;
    float Mx = -INFINITY;
    for (int c = 0; c < split; ++c)
        Mx = fmaxf(Mx, partML[((size_t)c * N + n) * 2]);
    float L = 0.f, acc = 0.f;
    for (int c = 0; c < split; ++c) {
        float w = __expf(partML[((size_t)c * N + n) * 2] - Mx);
        L   += w * partML[((size_t)c * N + n) * 2 + 1];
        acc += w * partO[((size_t)c * N + n) * 128 + d];
    }
    float evals = acc / L;
    if (evals != evals) evals = 0.f;   // match reference's isnan guard
    float iv = rowc[n * 4 + 2];
    out[(size_t)n * 128 + d] = (evals - x[(size_t)n * 128 + d]) * iv;
}

// ---------------------------------------------------------------- launch
extern "C" void kernel_launch(void* const* d_in, const int* in_sizes, int n_in,
                              void* d_out, int out_size, void* d_ws, size_t ws_size,
                              hipStream_t stream) {
    const float* x     = (const float*)d_in[0];
    const float* t     = (const float*)d_in[1];
    const float* train = (const float*)d_in[2];
    float* out = (float*)d_out;

    const int N = in_sizes[1];            // 4096
    const int D = 128;
    const int M = in_sizes[2] / D;        // 16384

    char* ws = (char*)d_ws;
    size_t off = 0;
    auto alloc = [&](size_t bytes) -> void* {
        void* p = ws + off;
        off = (off + bytes + 255) & ~(size_t)255;
        return p;
    };
    u16* Khi   = (u16*)alloc((size_t)M * D * 2);
    u16* Klo   = (u16*)alloc((size_t)M * D * 2);
    u16* Vt    = (u16*)alloc((size_t)M * D * 2);
    u16* Qhi   = (u16*)alloc((size_t)N * D * 2);
    u16* Qlo   = (u16*)alloc((size_t)N * D * 2);
    float* rowc = (float*)alloc((size_t)N * 16);
    float* y2   = (float*)alloc((size_t)M * 4);
    size_t base = off;
    size_t per  = (size_t)N * D * 4 + (size_t)N * 8 + 512;   // partO + partML per chunk
    int split = 16;
    while (split > 1 && base + per * split > ws_size) split >>= 1;
    float* partO  = (float*)alloc((size_t)split * N * D * 4);
    float* partML = (float*)alloc((size_t)split * N * 8);

    rows_kernel<<<(N + 255) / 256, 256, 0, stream>>>(t, rowc, N);
    conv_hilo<<<(N * D / 4 + 255) / 256, 256, 0, stream>>>(x, Qhi, Qlo, N * D / 4);
    conv_hilo<<<(M * D / 4 + 255) / 256, 256, 0, stream>>>(train, Khi, Klo, M * D / 4);
    vt_y2_kernel<<<M / 4, 256, 0, stream>>>(train, Vt, y2, M);

    int mchunk = M / split;
    dim3 grid(N / 64, split);
    flash_kernel<<<grid, 256, 0, stream>>>(Khi, Klo, Vt, Qhi, Qlo, rowc, y2,
                                           partO, partML, N, M, mchunk);
    combine_kernel<<<N, 128, 0, stream>>>(partO, partML, x, rowc, out, N, split);
}